// Round 17
// baseline (162.629 us; speedup 1.0000x reference)
//
#include <hip/hip_runtime.h>
#include <math.h>

#define NN 50000
#define NE 800000
#define FD 128      // IN == HC == 128
#define NB 64
#define NBUK 196            // ceil(NN/256) buckets of 256 dst nodes
#define NCHK 256            // histogram/scatter chunks
#define CHK 3125            // NE / NCHK
#define CAP 6144            // LDS staging capacity per bucket (mean 4082, std ~64)
#define NBLK 782            // ceil(NN/64) 64-row tiles for the linears

typedef __attribute__((ext_vector_type(8))) short short8v;
typedef __attribute__((ext_vector_type(4))) float f32x4;
typedef _Float16 h2 __attribute__((ext_vector_type(2)));
typedef _Float16 h8 __attribute__((ext_vector_type(8)));

// ---------------- fp16 helpers ----------------
__device__ __forceinline__ unsigned short f2h(float f) {
  return __builtin_bit_cast(unsigned short, (_Float16)f);
}
__device__ __forceinline__ float h2f(unsigned short u) {
  return (float)__builtin_bit_cast(_Float16, u);
}

// fp16-single image coords for node n, 32-lane id holding cols 4*lane..4*lane+3
__device__ __forceinline__ size_t img_base(int n, int lane) {
  int lrow = n & 63, blk = n >> 6;
  int kh = lane >> 4, s7 = (lane >> 1) & 7, off4 = (lane & 1) * 4;
  return (size_t)blk * 8192 + kh * 4096 + lrow * 64 + 8 * (s7 ^ (lrow & 7)) + off4;
}

// ================= K1: [hist2d | wprep | xprep] — all independent, no global atomics =====
__global__ __launch_bounds__(256) void k_prep1(const float* __restrict__ W0,
    const float* __restrict__ W1, const float* __restrict__ W2,
    const float* __restrict__ W3, const float* __restrict__ W4,
    unsigned short* __restrict__ wimg,
    const int* __restrict__ dst, int* __restrict__ hist2d,
    const float* __restrict__ x, unsigned short* __restrict__ ximg) {
  __shared__ int bh[NBUK];
  int bx = blockIdx.x;
  if (bx < NCHK) {
    // ---- per-chunk bucket histogram, private row (no global atomics) ----
    int t = threadIdx.x;
    for (int i = t; i < NBUK; i += 256) bh[i] = 0;
    __syncthreads();
    int e0 = bx * CHK, e1 = e0 + CHK;
    if (e1 > NE) e1 = NE;
    for (int e = e0 + t; e < e1; e += 256) atomicAdd(&bh[dst[e] >> 8], 1);
    __syncthreads();
    for (int i = t; i < NBUK; i += 256) hist2d[bx * NBUK + i] = bh[i];
  } else if (bx < NCHK + 40) {
    // ---- wprep: W -> fp16-single pre-swizzled images ----
    int id = (bx - NCHK) * 256 + threadIdx.x;
    if (id >= 5 * 2048) return;
    int w = id >> 11, rem = id & 2047;
    int row = rem >> 4, slot = rem & 15;
    const float* Wp = (w == 0) ? W0 : (w == 1) ? W1 : (w == 2) ? W2 : (w == 3) ? W3 : W4;
    const float* sp = &Wp[row * 128 + slot * 8];
    int kh = slot >> 3, s7 = slot & 7;
    int d = ((w * 2 + kh) * 8192) + row * 64 + 8 * (s7 ^ (row & 7));
    short8v hv;
    #pragma unroll
    for (int j = 0; j < 8; ++j)
      hv[j] = (short)f2h(sp[j]);
    *(short8v*)&wimg[d] = hv;
  } else {
    // ---- xprep: pack x into fp16-single swizzled A-image ----
    int id = (bx - NCHK - 40) * 256 + threadIdx.x;   // < NN*16 = 800000 exactly
    int row = id >> 4, slot = id & 15;
    const float* sp = &x[(size_t)row * 128 + slot * 8];
    int blk = row >> 6, lrow = row & 63, kh = slot >> 3, s7 = slot & 7;
    size_t hoff = (size_t)blk * 8192 + kh * 4096 + lrow * 64 + 8 * (s7 ^ (lrow & 7));
    short8v hv;
    #pragma unroll
    for (int j = 0; j < 8; ++j)
      hv[j] = (short)f2h(sp[j]);
    *(short8v*)&ximg[hoff] = hv;
  }
}

// ================= K2a: per-bucket scan over 256 chunk counts =================
__global__ __launch_bounds__(256) void k_colscan(const int* __restrict__ hist2d,
    int* __restrict__ coff, int* __restrict__ btot) {
  __shared__ int ws[4];
  int b = blockIdx.x, t = threadIdx.x;
  int v = hist2d[t * NBUK + b];
  int lane = t & 63, wv = t >> 6;
  int s = v;
  #pragma unroll
  for (int off = 1; off < 64; off <<= 1) {
    int y = __shfl_up(s, off, 64);
    if (lane >= off) s += y;
  }
  if (lane == 63) ws[wv] = s;
  __syncthreads();
  if (t == 0) {
    int r = 0;
    #pragma unroll
    for (int i = 0; i < 4; ++i) { int x = ws[i]; ws[i] = r; r += x; }
  }
  __syncthreads();
  int excl = s - v + ws[wv];
  coff[b * 256 + t] = excl;
  if (t == 255) btot[b] = excl + v;
}

// ================= K2b: scan of 196 bucket totals -> bbase (+ zero ssrc pad) =========
__global__ __launch_bounds__(256) void k_bscan2(const int* __restrict__ btot,
                                                int* __restrict__ bbase,
                                                int* __restrict__ ssrc) {
  __shared__ int wsum[4];
  int t = threadIdx.x;
  int v = (t < NBUK) ? btot[t] : 0;
  int lane = t & 63, wv = t >> 6;
  int s = v;
  #pragma unroll
  for (int off = 1; off < 64; off <<= 1) {
    int y = __shfl_up(s, off, 64);
    if (lane >= off) s += y;
  }
  if (lane == 63) wsum[wv] = s;
  __syncthreads();
  if (t == 0) {
    int r = 0;
    #pragma unroll
    for (int i = 0; i < 4; ++i) { int x = wsum[i]; wsum[i] = r; r += x; }
  }
  __syncthreads();
  int excl = s - v + wsum[wv];
  if (t < NBUK) bbase[t] = excl;
  if (t == NBUK - 1) bbase[NBUK] = excl + v;
  if (t >= 200 && t < 208) ssrc[NE + (t - 200)] = 0;   // zero the prefetch pad
}

// ================= K3: scatter with precomputed offsets (LDS atomics only) =========
// pkt = (src << 8) | (dst & 255)
__global__ __launch_bounds__(256) void k_bscatter(const int* __restrict__ src,
    const int* __restrict__ dst, const int* __restrict__ bbase,
    const int* __restrict__ coff, int* __restrict__ tmpv) {
  __shared__ int bb[NBUK];
  __shared__ int brun[NBUK];
  int c = blockIdx.x, t = threadIdx.x;
  for (int i = t; i < NBUK; i += 256) {
    bb[i] = bbase[i] + coff[i * 256 + c];
    brun[i] = 0;
  }
  __syncthreads();
  int e0 = c * CHK, e1 = e0 + CHK;
  if (e1 > NE) e1 = NE;
  for (int e = e0 + t; e < e1; e += 256) {
    int d = dst[e];
    int bk = d >> 8;
    int p = bb[bk] + atomicAdd(&brun[bk], 1);
    tmpv[p] = (src[e] << 8) | (d & 255);
  }
}

// ---------------- MFMA linear body: fp16 A x fp16 W (single), 1 MFMA/slice ----------
__device__ __forceinline__ void linm2_body(
    const unsigned short* __restrict__ aimg,
    const unsigned short* __restrict__ w_img,
    int wimg, const float* __restrict__ bias,
    _Float16* __restrict__ out_h, int blk, char* smem) {
  unsigned short* s_a = (unsigned short*)smem;           // 8 KB
  unsigned short* s_w = s_a + 4096;                      // 16 KB
  const int tid = threadIdx.x;
  const int lane = tid & 63;
  const int wv = tid >> 6;
  const int m0 = (wv >> 2) * 32;
  const int n0 = (wv & 3) * 32;
  const int rbase = blk * 64;
  const int g = lane >> 4, lr = lane & 15;

  f32x4 acc[2][2];
  #pragma unroll
  for (int mt = 0; mt < 2; ++mt)
    #pragma unroll
    for (int nt = 0; nt < 2; ++nt)
      acc[mt][nt] = (f32x4){0.f, 0.f, 0.f, 0.f};

  for (int kh = 0; kh < 2; ++kh) {
    if (kh) __syncthreads();
    {
      const short8v* asrc = (const short8v*)(aimg + (size_t)blk * 8192 + kh * 4096);
      ((short8v*)s_a)[tid] = asrc[tid];                  // 512 x 16B = 8 KB
    }
    {
      const short8v* wsrc = (const short8v*)(w_img + (size_t)(wimg * 2 + kh) * 8192);
      short8v* wd = (short8v*)s_w;
      wd[tid] = wsrc[tid];
      wd[512 + tid] = wsrc[512 + tid];                   // 16 KB
    }
    __syncthreads();
    #pragma unroll
    for (int ks = 0; ks < 2; ++ks) {
      const int slot = ks * 4 + g;
      h8 a[2];
      #pragma unroll
      for (int mt = 0; mt < 2; ++mt) {
        int row = m0 + mt * 16 + lr;
        int idx = row * 64 + 8 * (slot ^ (row & 7));
        a[mt] = __builtin_bit_cast(h8, *(const short8v*)&s_a[idx]);
      }
      #pragma unroll
      for (int nt = 0; nt < 2; ++nt) {
        int row2 = n0 + nt * 16 + lr;
        int idx2 = row2 * 64 + 8 * (slot ^ (row2 & 7));
        h8 b = __builtin_bit_cast(h8, *(const short8v*)&s_w[idx2]);
        #pragma unroll
        for (int mt = 0; mt < 2; ++mt)
          acc[mt][nt] = __builtin_amdgcn_mfma_f32_16x16x32_f16(a[mt], b, acc[mt][nt], 0, 0, 0);
      }
    }
  }
  #pragma unroll
  for (int nt = 0; nt < 2; ++nt) {
    float bv = bias[n0 + nt * 16 + lr];
    #pragma unroll
    for (int mt = 0; mt < 2; ++mt)
      #pragma unroll
      for (int i = 0; i < 4; ++i) {
        int r = rbase + m0 + mt * 16 + 4 * g + i;
        if (r < NN) {
          float vv = acc[mt][nt][i] + bv;
          out_h[(size_t)r * 128 + n0 + nt * 16 + lr] = (_Float16)vv;
        }
      }
  }
}

// ================= K4: [bcsr | linm2 layer-1 (3 matrices)] =================
__global__ __launch_bounds__(512, 8) void k_csrlin(
    const int* __restrict__ tmpv, const int* __restrict__ bbase,
    int* __restrict__ offs, int* __restrict__ ssrc,
    const unsigned short* __restrict__ ximg,
    const unsigned short* __restrict__ w_img,
    const float* __restrict__ bl1, const float* __restrict__ br1, const float* __restrict__ bres,
    _Float16* __restrict__ xl, _Float16* __restrict__ xr,
    _Float16* __restrict__ res) {
  __shared__ __align__(16) char smem[28672];   // bcsr needs 26.7 KB; GEMM uses 24 KB
  int bx = blockIdx.x;
  if (bx < NBUK) {
    int* sdeg = (int*)smem;
    int* scur = sdeg + 256;
    int* wsum = scur + 256;
    int* lsrc = wsum + 16;
    int b = bx, t = threadIdx.x;
    int es = bbase[b], ee = bbase[b + 1];
    int cnt = ee - es;
    if (t < 256) sdeg[t] = 0;
    __syncthreads();
    for (int i = t; i < cnt; i += 512) atomicAdd(&sdeg[tmpv[es + i] & 255], 1);
    __syncthreads();
    int v = 0, s = 0;
    int lane = t & 63, wv = t >> 6;
    if (t < 256) {
      v = sdeg[t];
      s = v;
      #pragma unroll
      for (int off = 1; off < 64; off <<= 1) {
        int y = __shfl_up(s, off, 64);
        if (lane >= off) s += y;
      }
      if (lane == 63) wsum[wv] = s;
    }
    __syncthreads();
    if (t == 0) {
      int r = 0;
      #pragma unroll
      for (int i = 0; i < 4; ++i) { int x2 = wsum[i]; wsum[i] = r; r += x2; }
    }
    __syncthreads();
    if (t < 256) {
      int excl = s - v + wsum[wv];
      scur[t] = excl;
      int node = b * 256 + t;
      if (node < NN) offs[node] = es + excl;
    }
    if (b == 0 && t == 0) offs[NN] = NE;
    __syncthreads();
    if (cnt <= CAP) {
      for (int i = t; i < cnt; i += 512) {
        int pkt = tmpv[es + i];
        int p = atomicAdd(&scur[pkt & 255], 1);
        lsrc[p] = pkt >> 8;
      }
      __syncthreads();
      for (int i = t; i < cnt; i += 512) ssrc[es + i] = lsrc[i];
    } else {
      for (int i = t; i < cnt; i += 512) {
        int pkt = tmpv[es + i];
        int p = atomicAdd(&scur[pkt & 255], 1);
        ssrc[es + p] = pkt >> 8;
      }
    }
  } else {
    int bf = bx - NBUK;
    int w = bf / NBLK, blk = bf % NBLK;
    const float* bias = (w == 0) ? bl1 : (w == 1) ? br1 : bres;
    _Float16* oh = (w == 0) ? xl : (w == 1) ? xr : res;
    linm2_body(ximg, w_img, w, bias, oh, blk, smem);
  }
}

// ================= K6: linm2 layer-2 (2 matrices) =================
__global__ __launch_bounds__(512, 8) void k_lin2(
    const unsigned short* __restrict__ himg,
    const unsigned short* __restrict__ w_img,
    const float* __restrict__ bl2, const float* __restrict__ br2,
    _Float16* __restrict__ xl, _Float16* __restrict__ xr) {
  __shared__ __align__(16) char smem[28672];
  int w = blockIdx.y;
  linm2_body(himg, w_img, 3 + w, (w == 0) ? bl2 : br2,
             (w == 0) ? xl : xr, blockIdx.x, smem);
}

// ---------------- GATv2 core: fp16 packed edge math, software-pipelined gathers ------
__device__ __forceinline__ float4 gat_core(const _Float16* __restrict__ xl,
    const _Float16* __restrict__ xr, const int* __restrict__ offs,
    const int* __restrict__ ssrc, const float* __restrict__ att,
    const float* __restrict__ bias, int n, int lane) {
  float4 att4 = ((const float4*)att)[lane];
  h2 att01 = {(_Float16)att4.x, (_Float16)att4.y};
  h2 att23 = {(_Float16)att4.z, (_Float16)att4.w};
  uint2 xru = ((const uint2*)xr)[(size_t)n * 32 + lane];
  h2 xr01 = __builtin_bit_cast(h2, xru.x);
  h2 xr23 = __builtin_bit_cast(h2, xru.y);
  const h2 k02 = {(_Float16)0.2f, (_Float16)0.2f};
  int e0 = offs[n], e1 = offs[n + 1];
  float den = 0.f;
  float4 acc = make_float4(0.f, 0.f, 0.f, 0.f);
  int e = e0;
  int nb = (e1 - e0) >> 2;

  uint2 u[4];
  int idn[4];
  if (nb > 0) {
    #pragma unroll
    for (int j = 0; j < 4; ++j) {
      int s = ssrc[e + j];
      u[j] = ((const uint2*)xl)[(size_t)s * 32 + lane];
    }
    #pragma unroll
    for (int j = 0; j < 4; ++j) idn[j] = ssrc[e + 4 + j];   // pad-safe (ssrc has 8 zeroed extra)
  }
  for (int g = 1; g < nb; ++g) {
    uint2 un[4];
    #pragma unroll
    for (int j = 0; j < 4; ++j)
      un[j] = ((const uint2*)xl)[(size_t)idn[j] * 32 + lane];
    int idn2[4];
    #pragma unroll
    for (int j = 0; j < 4; ++j) idn2[j] = ssrc[e + 8 + j];  // pad-safe
    #pragma unroll
    for (int j = 0; j < 4; ++j) {
      h2 v01 = __builtin_bit_cast(h2, u[j].x);
      h2 v23 = __builtin_bit_cast(h2, u[j].y);
      h2 t01 = v01 + xr01;
      h2 t23 = v23 + xr23;
      h2 l01 = __builtin_elementwise_max(t01, t01 * k02);
      h2 l23 = __builtin_elementwise_max(t23, t23 * k02);
      float p = __builtin_amdgcn_fdot2(l01, att01, 0.f, false);
      p = __builtin_amdgcn_fdot2(l23, att23, p, false);
      p += __shfl_xor(p, 1, 64); p += __shfl_xor(p, 2, 64); p += __shfl_xor(p, 4, 64);
      float w = __expf(p);
      den += w;
      acc.x += w * (float)v01[0];
      acc.y += w * (float)v01[1];
      acc.z += w * (float)v23[0];
      acc.w += w * (float)v23[1];
    }
    e += 4;
    #pragma unroll
    for (int j = 0; j < 4; ++j) { u[j] = un[j]; idn[j] = idn2[j]; }
  }
  if (nb > 0) {
    #pragma unroll
    for (int j = 0; j < 4; ++j) {
      h2 v01 = __builtin_bit_cast(h2, u[j].x);
      h2 v23 = __builtin_bit_cast(h2, u[j].y);
      h2 t01 = v01 + xr01;
      h2 t23 = v23 + xr23;
      h2 l01 = __builtin_elementwise_max(t01, t01 * k02);
      h2 l23 = __builtin_elementwise_max(t23, t23 * k02);
      float p = __builtin_amdgcn_fdot2(l01, att01, 0.f, false);
      p = __builtin_amdgcn_fdot2(l23, att23, p, false);
      p += __shfl_xor(p, 1, 64); p += __shfl_xor(p, 2, 64); p += __shfl_xor(p, 4, 64);
      float w = __expf(p);
      den += w;
      acc.x += w * (float)v01[0];
      acc.y += w * (float)v01[1];
      acc.z += w * (float)v23[0];
      acc.w += w * (float)v23[1];
    }
    e += 4;
  }
  for (; e < e1; ++e) {
    int s = ssrc[e];
    uint2 uu = ((const uint2*)xl)[(size_t)s * 32 + lane];
    h2 v01 = __builtin_bit_cast(h2, uu.x);
    h2 v23 = __builtin_bit_cast(h2, uu.y);
    h2 t01 = v01 + xr01;
    h2 t23 = v23 + xr23;
    h2 l01 = __builtin_elementwise_max(t01, t01 * k02);
    h2 l23 = __builtin_elementwise_max(t23, t23 * k02);
    float p = __builtin_amdgcn_fdot2(l01, att01, 0.f, false);
    p = __builtin_amdgcn_fdot2(l23, att23, p, false);
    p += __shfl_xor(p, 1, 64); p += __shfl_xor(p, 2, 64); p += __shfl_xor(p, 4, 64);
    float w = __expf(p);
    den += w;
    acc.x += w * (float)v01[0];
    acc.y += w * (float)v01[1];
    acc.z += w * (float)v23[0];
    acc.w += w * (float)v23[1];
  }
  float inv = (den > 0.f) ? 1.f / den : 0.f;
  float4 b4 = ((const float4*)bias)[lane];
  float4 o;
  o.x = fmaxf(acc.x * inv + b4.x, 0.f);
  o.y = fmaxf(acc.y * inv + b4.y, 0.f);
  o.z = fmaxf(acc.z * inv + b4.z, 0.f);
  o.w = fmaxf(acc.w * inv + b4.w, 0.f);
  return o;
}

// ================= K5: GAT layer 1 — writes ONLY the fp16 himg image =================
__global__ __launch_bounds__(256) void k_gat1(const _Float16* __restrict__ xl,
    const _Float16* __restrict__ xr, const int* __restrict__ offs,
    const int* __restrict__ ssrc, const float* __restrict__ att,
    const float* __restrict__ bias, const _Float16* __restrict__ resid,
    unsigned short* __restrict__ himg) {
  int grp = threadIdx.x >> 5;
  int lane = threadIdx.x & 31;
  int n = blockIdx.x * 8 + grp;     // NN % 8 == 0: always valid
  float4 o = gat_core(xl, xr, offs, ssrc, att, bias, n, lane);
  uint2 ru = ((const uint2*)resid)[(size_t)n * 32 + lane];
  h2 r01 = __builtin_bit_cast(h2, ru.x);
  h2 r23 = __builtin_bit_cast(h2, ru.y);
  o.x += (float)r01[0]; o.y += (float)r01[1];
  o.z += (float)r23[0]; o.w += (float)r23[1];
  size_t base = img_base(n, lane);
  ushort4 hv;
  hv.x = f2h(o.x); hv.y = f2h(o.y); hv.z = f2h(o.z); hv.w = f2h(o.w);
  *(ushort4*)&himg[base] = hv;
}

// ================= K7: GAT layer 2 + fused mean-pool accumulation =================
__global__ __launch_bounds__(256) void k_gatpool(const _Float16* __restrict__ xl,
    const _Float16* __restrict__ xr, const int* __restrict__ offs,
    const int* __restrict__ ssrc, const float* __restrict__ att,
    const float* __restrict__ bias, const unsigned short* __restrict__ himg,
    const int* __restrict__ batch, float* __restrict__ pooled) {
  __shared__ float sm[8][128];
  __shared__ int sbat[8];
  int grp = threadIdx.x >> 5;
  int lane = threadIdx.x & 31;
  int n = blockIdx.x * 8 + grp;
  float4 o = gat_core(xl, xr, offs, ssrc, att, bias, n, lane);
  size_t base = img_base(n, lane);
  ushort4 rh = *(const ushort4*)&himg[base];
  o.x += h2f(rh.x); o.y += h2f(rh.y); o.z += h2f(rh.z); o.w += h2f(rh.w);
  *(float4*)&sm[grp][lane * 4] = o;
  if (threadIdx.x < 8) sbat[threadIdx.x] = batch[blockIdx.x * 8 + threadIdx.x];
  __syncthreads();
  int t = threadIdx.x;
  if (t < 128) {
    float run = sm[0][t];
    int cb = sbat[0];
    #pragma unroll
    for (int g2 = 1; g2 < 8; ++g2) {
      int bb = sbat[g2];
      if (bb != cb) { atomicAdd(&pooled[cb * FD + t], run); run = 0.f; cb = bb; }
      run += sm[g2][t];
    }
    atomicAdd(&pooled[cb * FD + t], run);
  }
}

// ================= K8: MLP head =================
__global__ __launch_bounds__(128) void k_mlp(const float* __restrict__ pooled,
    const int* __restrict__ batch, const float* __restrict__ domain,
    const float* __restrict__ Wg, const float* __restrict__ bg,
    const float* __restrict__ Wd, const float* __restrict__ bd,
    const float* __restrict__ Wf1, const float* __restrict__ bf1,
    const float* __restrict__ Wf2, const float* __restrict__ bf2,
    const float* __restrict__ Wf3, const float* __restrict__ bf3,
    float* __restrict__ out) {
  __shared__ float z[192];
  __shared__ float z1[128];
  __shared__ float z2[64];
  __shared__ float pm[128];
  __shared__ int cnt;
  int b = blockIdx.x, t = threadIdx.x;
  if (t == 0) {
    int lo = 0, hi = NN;
    while (lo < hi) { int mid = (lo + hi) >> 1; if (batch[mid] < b) lo = mid + 1; else hi = mid; }
    int lb = lo; lo = 0; hi = NN;
    while (lo < hi) { int mid = (lo + hi) >> 1; if (batch[mid] < b + 1) lo = mid + 1; else hi = mid; }
    cnt = lo - lb;
  }
  __syncthreads();
  float invc = 1.f / fmaxf((float)cnt, 1.f);
  pm[t] = pooled[b * FD + t] * invc;
  __syncthreads();
  {
    float a = bg[t];
    for (int k = 0; k < 128; ++k) a += pm[k] * Wg[t * 128 + k];
    z[t] = fmaxf(a, 0.f);
  }
  if (t < 64) {
    float a = bd[t];
    for (int k = 0; k < 32; ++k) a += domain[b * 32 + k] * Wd[t * 32 + k];
    z[128 + t] = fmaxf(a, 0.f);
  }
  __syncthreads();
  {
    float a = bf1[t];
    for (int k = 0; k < 192; ++k) a += z[k] * Wf1[t * 192 + k];
    z1[t] = fmaxf(a, 0.f);
  }
  __syncthreads();
  if (t < 64) {
    float a = bf2[t];
    for (int k = 0; k < 128; ++k) a += z1[k] * Wf2[t * 128 + k];
    z2[t] = fmaxf(a, 0.f);
  }
  __syncthreads();
  if (t < 64) {
    float v = z2[t] * Wf3[t];
    for (int off = 1; off < 64; off <<= 1) v += __shfl_xor(v, off, 64);
    if (t == 0) out[b] = v + bf3[0];
  }
}

extern "C" void kernel_launch(void* const* d_in, const int* in_sizes, int n_in,
                              void* d_out, int out_size, void* d_ws, size_t ws_size,
                              hipStream_t stream) {
  const float* x      = (const float*)d_in[0];
  const float* domain = (const float*)d_in[1];
  const float* Wl1 = (const float*)d_in[2];  const float* bl1 = (const float*)d_in[3];
  const float* Wr1 = (const float*)d_in[4];  const float* br1 = (const float*)d_in[5];
  const float* att1= (const float*)d_in[6];  const float* bias1=(const float*)d_in[7];
  const float* Wl2 = (const float*)d_in[8];  const float* bl2 = (const float*)d_in[9];
  const float* Wr2 = (const float*)d_in[10]; const float* br2 = (const float*)d_in[11];
  const float* att2= (const float*)d_in[12]; const float* bias2=(const float*)d_in[13];
  const float* Wres= (const float*)d_in[14]; const float* bres= (const float*)d_in[15];
  const float* Wd  = (const float*)d_in[16]; const float* bd  = (const float*)d_in[17];
  const float* Wg  = (const float*)d_in[18]; const float* bg  = (const float*)d_in[19];
  const float* Wf1 = (const float*)d_in[20]; const float* bf1 = (const float*)d_in[21];
  const float* Wf2 = (const float*)d_in[22]; const float* bf2 = (const float*)d_in[23];
  const float* Wf3 = (const float*)d_in[24]; const float* bf3 = (const float*)d_in[25];
  const int* ei    = (const int*)d_in[26];
  const int* batch = (const int*)d_in[27];
  const int* esrc = ei;
  const int* edst = ei + NE;
  float* outp = (float*)d_out;

  char* p = (char*)d_ws;
  auto carve = [&](size_t bytes) { char* r = p; p += (bytes + 255) & ~(size_t)255; return r; };
  int* hist2d   = (int*)carve((size_t)NCHK * NBUK * 4);
  int* coff     = (int*)carve((size_t)NBUK * NCHK * 4);
  int* btot     = (int*)carve((size_t)NBUK * 4);
  int* bbase    = (int*)carve((size_t)(NBUK + 1) * 4);
  int* tmpv     = (int*)carve((size_t)NE * 4);
  int* ssrc     = (int*)carve((size_t)(NE + 8) * 4);   // +8 pad for gather prefetch
  int* offs     = (int*)carve((size_t)(NN + 1) * 4);
  unsigned short* wimg = (unsigned short*)carve((size_t)5 * 2 * 8192 * 2);
  unsigned short* ximg = (unsigned short*)carve((size_t)NBLK * 8192 * 2);  // fp16 A image (aliased as himg)
  _Float16* xl  = (_Float16*)carve((size_t)NN * FD * 2);
  _Float16* xr  = (_Float16*)carve((size_t)NN * FD * 2);
  _Float16* res = (_Float16*)carve((size_t)NN * FD * 2);
  float* pooled = (float*)carve((size_t)NB * FD * 4);
  unsigned short* himg = ximg;     // ximg dead after layer-1 linears; alias

  hipMemsetAsync(pooled, 0, (size_t)NB * FD * 4, stream);

  dim3 b256(256);
  // K1: [hist2d(256) | wprep(40) | xprep(3125)]
  hipLaunchKernelGGL(k_prep1, dim3(NCHK + 40 + 3125), b256, 0, stream,
                     Wl1, Wr1, Wres, Wl2, Wr2, wimg, edst, hist2d, x, ximg);
  // K2a: per-bucket chunk scan; K2b: bucket-base scan (+ ssrc pad zero)
  hipLaunchKernelGGL(k_colscan, dim3(NBUK), b256, 0, stream, hist2d, coff, btot);
  hipLaunchKernelGGL(k_bscan2, dim3(1), b256, 0, stream, btot, bbase, ssrc);
  // K3: scatter with precomputed offsets (no global atomics)
  hipLaunchKernelGGL(k_bscatter, dim3(NCHK), b256, 0, stream, esrc, edst, bbase, coff, tmpv);
  // K4: [bcsr(196) | linm2 layer-1 (3*NBLK)]
  hipLaunchKernelGGL(k_csrlin, dim3(NBUK + 3 * NBLK), dim3(512), 0, stream,
                     tmpv, bbase, offs, ssrc, ximg, wimg, bl1, br1, bres, xl, xr, res);
  // K5: GAT layer 1 -> himg
  hipLaunchKernelGGL(k_gat1, dim3(NN / 8), b256, 0, stream,
                     xl, xr, offs, ssrc, att1, bias1, res, himg);
  // K6: linm2 layer-2
  hipLaunchKernelGGL(k_lin2, dim3(NBLK, 2), dim3(512), 0, stream,
                     himg, wimg, bl2, br2, xl, xr);
  // K7: GAT layer 2 + pooled accumulation
  hipLaunchKernelGGL(k_gatpool, dim3(NN / 8), b256, 0, stream,
                     xl, xr, offs, ssrc, att2, bias2, himg, batch, pooled);
  // K8: MLP head
  hipLaunchKernelGGL(k_mlp, dim3(NB), dim3(128), 0, stream, pooled, batch, domain,
                     Wg, bg, Wd, bd, Wf1, bf1, Wf2, bf2, Wf3, bf3, outp);
}

// Round 18
// 155.443 us; speedup vs baseline: 1.0462x; 1.0462x over previous
//
#include <hip/hip_runtime.h>
#include <math.h>

#define NN 50000
#define NE 800000
#define FD 128      // IN == HC == 128
#define NB 64
#define NBUK 196            // ceil(NN/256) buckets of 256 dst nodes
#define NCHK 256            // histogram/scatter chunks
#define CHK 3125            // NE / NCHK
#define CAP 6144            // LDS staging capacity per bucket (mean 4082, std ~64)
#define NBLK 782            // ceil(NN/64) 64-row tiles for the linears

typedef __attribute__((ext_vector_type(8))) short short8v;
typedef __attribute__((ext_vector_type(4))) float f32x4;
typedef _Float16 h2 __attribute__((ext_vector_type(2)));
typedef _Float16 h8 __attribute__((ext_vector_type(8)));

// ---------------- fp16 helpers ----------------
__device__ __forceinline__ unsigned short f2h(float f) {
  return __builtin_bit_cast(unsigned short, (_Float16)f);
}
__device__ __forceinline__ float h2f(unsigned short u) {
  return (float)__builtin_bit_cast(_Float16, u);
}

// fp16-single image coords for node n, 32-lane id holding cols 4*lane..4*lane+3
__device__ __forceinline__ size_t img_base(int n, int lane) {
  int lrow = n & 63, blk = n >> 6;
  int kh = lane >> 4, s7 = (lane >> 1) & 7, off4 = (lane & 1) * 4;
  return (size_t)blk * 8192 + kh * 4096 + lrow * 64 + 8 * (s7 ^ (lrow & 7)) + off4;
}

// ================= K1: [hist2d | wprep | xprep] — all independent, no global atomics =====
__global__ __launch_bounds__(256) void k_prep1(const float* __restrict__ W0,
    const float* __restrict__ W1, const float* __restrict__ W2,
    const float* __restrict__ W3, const float* __restrict__ W4,
    unsigned short* __restrict__ wimg,
    const int* __restrict__ dst, int* __restrict__ hist2d,
    const float* __restrict__ x, unsigned short* __restrict__ ximg) {
  __shared__ int bh[NBUK];
  int bx = blockIdx.x;
  if (bx < NCHK) {
    // ---- per-chunk bucket histogram, private row (no global atomics) ----
    int t = threadIdx.x;
    for (int i = t; i < NBUK; i += 256) bh[i] = 0;
    __syncthreads();
    int e0 = bx * CHK, e1 = e0 + CHK;
    if (e1 > NE) e1 = NE;
    for (int e = e0 + t; e < e1; e += 256) atomicAdd(&bh[dst[e] >> 8], 1);
    __syncthreads();
    for (int i = t; i < NBUK; i += 256) hist2d[bx * NBUK + i] = bh[i];
  } else if (bx < NCHK + 40) {
    // ---- wprep: W -> fp16-single pre-swizzled images ----
    int id = (bx - NCHK) * 256 + threadIdx.x;
    if (id >= 5 * 2048) return;
    int w = id >> 11, rem = id & 2047;
    int row = rem >> 4, slot = rem & 15;
    const float* Wp = (w == 0) ? W0 : (w == 1) ? W1 : (w == 2) ? W2 : (w == 3) ? W3 : W4;
    const float* sp = &Wp[row * 128 + slot * 8];
    int kh = slot >> 3, s7 = slot & 7;
    int d = ((w * 2 + kh) * 8192) + row * 64 + 8 * (s7 ^ (row & 7));
    short8v hv;
    #pragma unroll
    for (int j = 0; j < 8; ++j)
      hv[j] = (short)f2h(sp[j]);
    *(short8v*)&wimg[d] = hv;
  } else {
    // ---- xprep: pack x into fp16-single swizzled A-image ----
    int id = (bx - NCHK - 40) * 256 + threadIdx.x;   // < NN*16 = 800000 exactly
    int row = id >> 4, slot = id & 15;
    const float* sp = &x[(size_t)row * 128 + slot * 8];
    int blk = row >> 6, lrow = row & 63, kh = slot >> 3, s7 = slot & 7;
    size_t hoff = (size_t)blk * 8192 + kh * 4096 + lrow * 64 + 8 * (s7 ^ (lrow & 7));
    short8v hv;
    #pragma unroll
    for (int j = 0; j < 8; ++j)
      hv[j] = (short)f2h(sp[j]);
    *(short8v*)&ximg[hoff] = hv;
  }
}

// ================= K2a: per-bucket scan over 256 chunk counts =================
__global__ __launch_bounds__(256) void k_colscan(const int* __restrict__ hist2d,
    int* __restrict__ coff, int* __restrict__ btot) {
  __shared__ int ws[4];
  int b = blockIdx.x, t = threadIdx.x;
  int v = hist2d[t * NBUK + b];
  int lane = t & 63, wv = t >> 6;
  int s = v;
  #pragma unroll
  for (int off = 1; off < 64; off <<= 1) {
    int y = __shfl_up(s, off, 64);
    if (lane >= off) s += y;
  }
  if (lane == 63) ws[wv] = s;
  __syncthreads();
  if (t == 0) {
    int r = 0;
    #pragma unroll
    for (int i = 0; i < 4; ++i) { int x = ws[i]; ws[i] = r; r += x; }
  }
  __syncthreads();
  int excl = s - v + ws[wv];
  coff[b * 256 + t] = excl;
  if (t == 255) btot[b] = excl + v;
}

// ================= K2b: scan of 196 bucket totals -> bbase (+ zero pooled) =========
__global__ __launch_bounds__(256) void k_bscan2(const int* __restrict__ btot,
                                                int* __restrict__ bbase,
                                                float* __restrict__ pooled) {
  __shared__ int wsum[4];
  int t = threadIdx.x;
  int v = (t < NBUK) ? btot[t] : 0;
  int lane = t & 63, wv = t >> 6;
  int s = v;
  #pragma unroll
  for (int off = 1; off < 64; off <<= 1) {
    int y = __shfl_up(s, off, 64);
    if (lane >= off) s += y;
  }
  if (lane == 63) wsum[wv] = s;
  __syncthreads();
  if (t == 0) {
    int r = 0;
    #pragma unroll
    for (int i = 0; i < 4; ++i) { int x = wsum[i]; wsum[i] = r; r += x; }
  }
  __syncthreads();
  int excl = s - v + wsum[wv];
  if (t < NBUK) bbase[t] = excl;
  if (t == NBUK - 1) bbase[NBUK] = excl + v;
  // zero the pooled accumulator (replaces the pathological runtime fill kernel)
  float4 z4 = make_float4(0.f, 0.f, 0.f, 0.f);
  #pragma unroll
  for (int i = 0; i < 8; ++i)
    ((float4*)pooled)[i * 256 + t] = z4;   // 8*256*4 = 8192 floats
}

// ================= K3: scatter with precomputed offsets (LDS atomics only) =========
// pkt = (src << 8) | (dst & 255)
__global__ __launch_bounds__(256) void k_bscatter(const int* __restrict__ src,
    const int* __restrict__ dst, const int* __restrict__ bbase,
    const int* __restrict__ coff, int* __restrict__ tmpv) {
  __shared__ int bb[NBUK];
  __shared__ int brun[NBUK];
  int c = blockIdx.x, t = threadIdx.x;
  for (int i = t; i < NBUK; i += 256) {
    bb[i] = bbase[i] + coff[i * 256 + c];
    brun[i] = 0;
  }
  __syncthreads();
  int e0 = c * CHK, e1 = e0 + CHK;
  if (e1 > NE) e1 = NE;
  for (int e = e0 + t; e < e1; e += 256) {
    int d = dst[e];
    int bk = d >> 8;
    int p = bb[bk] + atomicAdd(&brun[bk], 1);
    tmpv[p] = (src[e] << 8) | (d & 255);
  }
}

// ---------------- MFMA linear body: fp16 A x fp16 W (single), 1 MFMA/slice ----------
__device__ __forceinline__ void linm2_body(
    const unsigned short* __restrict__ aimg,
    const unsigned short* __restrict__ w_img,
    int wimg, const float* __restrict__ bias,
    _Float16* __restrict__ out_h, int blk, char* smem) {
  unsigned short* s_a = (unsigned short*)smem;           // 8 KB
  unsigned short* s_w = s_a + 4096;                      // 16 KB
  const int tid = threadIdx.x;
  const int lane = tid & 63;
  const int wv = tid >> 6;
  const int m0 = (wv >> 2) * 32;
  const int n0 = (wv & 3) * 32;
  const int rbase = blk * 64;
  const int g = lane >> 4, lr = lane & 15;

  f32x4 acc[2][2];
  #pragma unroll
  for (int mt = 0; mt < 2; ++mt)
    #pragma unroll
    for (int nt = 0; nt < 2; ++nt)
      acc[mt][nt] = (f32x4){0.f, 0.f, 0.f, 0.f};

  for (int kh = 0; kh < 2; ++kh) {
    if (kh) __syncthreads();
    {
      const short8v* asrc = (const short8v*)(aimg + (size_t)blk * 8192 + kh * 4096);
      ((short8v*)s_a)[tid] = asrc[tid];                  // 512 x 16B = 8 KB
    }
    {
      const short8v* wsrc = (const short8v*)(w_img + (size_t)(wimg * 2 + kh) * 8192);
      short8v* wd = (short8v*)s_w;
      wd[tid] = wsrc[tid];
      wd[512 + tid] = wsrc[512 + tid];                   // 16 KB
    }
    __syncthreads();
    #pragma unroll
    for (int ks = 0; ks < 2; ++ks) {
      const int slot = ks * 4 + g;
      h8 a[2];
      #pragma unroll
      for (int mt = 0; mt < 2; ++mt) {
        int row = m0 + mt * 16 + lr;
        int idx = row * 64 + 8 * (slot ^ (row & 7));
        a[mt] = __builtin_bit_cast(h8, *(const short8v*)&s_a[idx]);
      }
      #pragma unroll
      for (int nt = 0; nt < 2; ++nt) {
        int row2 = n0 + nt * 16 + lr;
        int idx2 = row2 * 64 + 8 * (slot ^ (row2 & 7));
        h8 b = __builtin_bit_cast(h8, *(const short8v*)&s_w[idx2]);
        #pragma unroll
        for (int mt = 0; mt < 2; ++mt)
          acc[mt][nt] = __builtin_amdgcn_mfma_f32_16x16x32_f16(a[mt], b, acc[mt][nt], 0, 0, 0);
      }
    }
  }
  #pragma unroll
  for (int nt = 0; nt < 2; ++nt) {
    float bv = bias[n0 + nt * 16 + lr];
    #pragma unroll
    for (int mt = 0; mt < 2; ++mt)
      #pragma unroll
      for (int i = 0; i < 4; ++i) {
        int r = rbase + m0 + mt * 16 + 4 * g + i;
        if (r < NN) {
          float vv = acc[mt][nt][i] + bv;
          out_h[(size_t)r * 128 + n0 + nt * 16 + lr] = (_Float16)vv;
        }
      }
  }
}

// ================= K4: [bcsr | linm2 layer-1 (3 matrices)] =================
__global__ __launch_bounds__(512, 8) void k_csrlin(
    const int* __restrict__ tmpv, const int* __restrict__ bbase,
    int* __restrict__ offs, int* __restrict__ ssrc,
    const unsigned short* __restrict__ ximg,
    const unsigned short* __restrict__ w_img,
    const float* __restrict__ bl1, const float* __restrict__ br1, const float* __restrict__ bres,
    _Float16* __restrict__ xl, _Float16* __restrict__ xr,
    _Float16* __restrict__ res) {
  __shared__ __align__(16) char smem[28672];   // bcsr needs 26.7 KB; GEMM uses 24 KB
  int bx = blockIdx.x;
  if (bx < NBUK) {
    int* sdeg = (int*)smem;
    int* scur = sdeg + 256;
    int* wsum = scur + 256;
    int* lsrc = wsum + 16;
    int b = bx, t = threadIdx.x;
    int es = bbase[b], ee = bbase[b + 1];
    int cnt = ee - es;
    if (t < 256) sdeg[t] = 0;
    __syncthreads();
    for (int i = t; i < cnt; i += 512) atomicAdd(&sdeg[tmpv[es + i] & 255], 1);
    __syncthreads();
    int v = 0, s = 0;
    int lane = t & 63, wv = t >> 6;
    if (t < 256) {
      v = sdeg[t];
      s = v;
      #pragma unroll
      for (int off = 1; off < 64; off <<= 1) {
        int y = __shfl_up(s, off, 64);
        if (lane >= off) s += y;
      }
      if (lane == 63) wsum[wv] = s;
    }
    __syncthreads();
    if (t == 0) {
      int r = 0;
      #pragma unroll
      for (int i = 0; i < 4; ++i) { int x2 = wsum[i]; wsum[i] = r; r += x2; }
    }
    __syncthreads();
    if (t < 256) {
      int excl = s - v + wsum[wv];
      scur[t] = excl;
      int node = b * 256 + t;
      if (node < NN) offs[node] = es + excl;
    }
    if (b == 0 && t == 0) offs[NN] = NE;
    __syncthreads();
    if (cnt <= CAP) {
      for (int i = t; i < cnt; i += 512) {
        int pkt = tmpv[es + i];
        int p = atomicAdd(&scur[pkt & 255], 1);
        lsrc[p] = pkt >> 8;
      }
      __syncthreads();
      for (int i = t; i < cnt; i += 512) ssrc[es + i] = lsrc[i];
    } else {
      for (int i = t; i < cnt; i += 512) {
        int pkt = tmpv[es + i];
        int p = atomicAdd(&scur[pkt & 255], 1);
        ssrc[es + p] = pkt >> 8;
      }
    }
  } else {
    int bf = bx - NBUK;
    int w = bf / NBLK, blk = bf % NBLK;
    const float* bias = (w == 0) ? bl1 : (w == 1) ? br1 : bres;
    _Float16* oh = (w == 0) ? xl : (w == 1) ? xr : res;
    linm2_body(ximg, w_img, w, bias, oh, blk, smem);
  }
}

// ================= K6: linm2 layer-2 (2 matrices) =================
__global__ __launch_bounds__(512, 8) void k_lin2(
    const unsigned short* __restrict__ himg,
    const unsigned short* __restrict__ w_img,
    const float* __restrict__ bl2, const float* __restrict__ br2,
    _Float16* __restrict__ xl, _Float16* __restrict__ xr) {
  __shared__ __align__(16) char smem[28672];
  int w = blockIdx.y;
  linm2_body(himg, w_img, 3 + w, (w == 0) ? bl2 : br2,
             (w == 0) ? xl : xr, blockIdx.x, smem);
}

// ---------------- GATv2 core: fp16 packed edge math, no-max softmax, 4-wide MLP ------
__device__ __forceinline__ float4 gat_core(const _Float16* __restrict__ xl,
    const _Float16* __restrict__ xr, const int* __restrict__ offs,
    const int* __restrict__ ssrc, const float* __restrict__ att,
    const float* __restrict__ bias, int n, int lane) {
  float4 att4 = ((const float4*)att)[lane];
  h2 att01 = {(_Float16)att4.x, (_Float16)att4.y};
  h2 att23 = {(_Float16)att4.z, (_Float16)att4.w};
  uint2 xru = ((const uint2*)xr)[(size_t)n * 32 + lane];
  h2 xr01 = __builtin_bit_cast(h2, xru.x);
  h2 xr23 = __builtin_bit_cast(h2, xru.y);
  const h2 k02 = {(_Float16)0.2f, (_Float16)0.2f};
  int e0 = offs[n], e1 = offs[n + 1];
  float den = 0.f;
  float4 acc = make_float4(0.f, 0.f, 0.f, 0.f);
  int e = e0;
  for (; e + 3 < e1; e += 4) {
    uint2 u[4];
    #pragma unroll
    for (int j = 0; j < 4; ++j) {
      int s = ssrc[e + j];
      u[j] = ((const uint2*)xl)[(size_t)s * 32 + lane];
    }
    #pragma unroll
    for (int j = 0; j < 4; ++j) {
      h2 v01 = __builtin_bit_cast(h2, u[j].x);
      h2 v23 = __builtin_bit_cast(h2, u[j].y);
      h2 t01 = v01 + xr01;
      h2 t23 = v23 + xr23;
      h2 l01 = __builtin_elementwise_max(t01, t01 * k02);
      h2 l23 = __builtin_elementwise_max(t23, t23 * k02);
      float p = __builtin_amdgcn_fdot2(l01, att01, 0.f, false);
      p = __builtin_amdgcn_fdot2(l23, att23, p, false);
      p += __shfl_xor(p, 1, 64); p += __shfl_xor(p, 2, 64); p += __shfl_xor(p, 4, 64);
      float w = __expf(p);
      den += w;
      acc.x += w * (float)v01[0];
      acc.y += w * (float)v01[1];
      acc.z += w * (float)v23[0];
      acc.w += w * (float)v23[1];
    }
  }
  for (; e < e1; ++e) {
    int s = ssrc[e];
    uint2 uu = ((const uint2*)xl)[(size_t)s * 32 + lane];
    h2 v01 = __builtin_bit_cast(h2, uu.x);
    h2 v23 = __builtin_bit_cast(h2, uu.y);
    h2 t01 = v01 + xr01;
    h2 t23 = v23 + xr23;
    h2 l01 = __builtin_elementwise_max(t01, t01 * k02);
    h2 l23 = __builtin_elementwise_max(t23, t23 * k02);
    float p = __builtin_amdgcn_fdot2(l01, att01, 0.f, false);
    p = __builtin_amdgcn_fdot2(l23, att23, p, false);
    p += __shfl_xor(p, 1, 64); p += __shfl_xor(p, 2, 64); p += __shfl_xor(p, 4, 64);
    float w = __expf(p);
    den += w;
    acc.x += w * (float)v01[0];
    acc.y += w * (float)v01[1];
    acc.z += w * (float)v23[0];
    acc.w += w * (float)v23[1];
  }
  float inv = (den > 0.f) ? 1.f / den : 0.f;
  float4 b4 = ((const float4*)bias)[lane];
  float4 o;
  o.x = fmaxf(acc.x * inv + b4.x, 0.f);
  o.y = fmaxf(acc.y * inv + b4.y, 0.f);
  o.z = fmaxf(acc.z * inv + b4.z, 0.f);
  o.w = fmaxf(acc.w * inv + b4.w, 0.f);
  return o;
}

// ================= K5: GAT layer 1 — writes ONLY the fp16 himg image =================
__global__ __launch_bounds__(256) void k_gat1(const _Float16* __restrict__ xl,
    const _Float16* __restrict__ xr, const int* __restrict__ offs,
    const int* __restrict__ ssrc, const float* __restrict__ att,
    const float* __restrict__ bias, const _Float16* __restrict__ resid,
    unsigned short* __restrict__ himg) {
  int grp = threadIdx.x >> 5;
  int lane = threadIdx.x & 31;
  int n = blockIdx.x * 8 + grp;     // NN % 8 == 0: always valid
  float4 o = gat_core(xl, xr, offs, ssrc, att, bias, n, lane);
  uint2 ru = ((const uint2*)resid)[(size_t)n * 32 + lane];
  h2 r01 = __builtin_bit_cast(h2, ru.x);
  h2 r23 = __builtin_bit_cast(h2, ru.y);
  o.x += (float)r01[0]; o.y += (float)r01[1];
  o.z += (float)r23[0]; o.w += (float)r23[1];
  size_t base = img_base(n, lane);
  ushort4 hv;
  hv.x = f2h(o.x); hv.y = f2h(o.y); hv.z = f2h(o.z); hv.w = f2h(o.w);
  *(ushort4*)&himg[base] = hv;
}

// ================= K7: GAT layer 2 + fused mean-pool accumulation =================
__global__ __launch_bounds__(256) void k_gatpool(const _Float16* __restrict__ xl,
    const _Float16* __restrict__ xr, const int* __restrict__ offs,
    const int* __restrict__ ssrc, const float* __restrict__ att,
    const float* __restrict__ bias, const unsigned short* __restrict__ himg,
    const int* __restrict__ batch, float* __restrict__ pooled) {
  __shared__ float sm[8][128];
  __shared__ int sbat[8];
  int grp = threadIdx.x >> 5;
  int lane = threadIdx.x & 31;
  int n = blockIdx.x * 8 + grp;
  float4 o = gat_core(xl, xr, offs, ssrc, att, bias, n, lane);
  size_t base = img_base(n, lane);
  ushort4 rh = *(const ushort4*)&himg[base];
  o.x += h2f(rh.x); o.y += h2f(rh.y); o.z += h2f(rh.z); o.w += h2f(rh.w);
  *(float4*)&sm[grp][lane * 4] = o;
  if (threadIdx.x < 8) sbat[threadIdx.x] = batch[blockIdx.x * 8 + threadIdx.x];
  __syncthreads();
  int t = threadIdx.x;
  if (t < 128) {
    float run = sm[0][t];
    int cb = sbat[0];
    #pragma unroll
    for (int g2 = 1; g2 < 8; ++g2) {
      int bb = sbat[g2];
      if (bb != cb) { atomicAdd(&pooled[cb * FD + t], run); run = 0.f; cb = bb; }
      run += sm[g2][t];
    }
    atomicAdd(&pooled[cb * FD + t], run);
  }
}

// ================= K8: MLP head =================
__global__ __launch_bounds__(128) void k_mlp(const float* __restrict__ pooled,
    const int* __restrict__ batch, const float* __restrict__ domain,
    const float* __restrict__ Wg, const float* __restrict__ bg,
    const float* __restrict__ Wd, const float* __restrict__ bd,
    const float* __restrict__ Wf1, const float* __restrict__ bf1,
    const float* __restrict__ Wf2, const float* __restrict__ bf2,
    const float* __restrict__ Wf3, const float* __restrict__ bf3,
    float* __restrict__ out) {
  __shared__ float z[192];
  __shared__ float z1[128];
  __shared__ float z2[64];
  __shared__ float pm[128];
  __shared__ int cnt;
  int b = blockIdx.x, t = threadIdx.x;
  if (t == 0) {
    int lo = 0, hi = NN;
    while (lo < hi) { int mid = (lo + hi) >> 1; if (batch[mid] < b) lo = mid + 1; else hi = mid; }
    int lb = lo; lo = 0; hi = NN;
    while (lo < hi) { int mid = (lo + hi) >> 1; if (batch[mid] < b + 1) lo = mid + 1; else hi = mid; }
    cnt = lo - lb;
  }
  __syncthreads();
  float invc = 1.f / fmaxf((float)cnt, 1.f);
  pm[t] = pooled[b * FD + t] * invc;
  __syncthreads();
  {
    float a = bg[t];
    for (int k = 0; k < 128; ++k) a += pm[k] * Wg[t * 128 + k];
    z[t] = fmaxf(a, 0.f);
  }
  if (t < 64) {
    float a = bd[t];
    for (int k = 0; k < 32; ++k) a += domain[b * 32 + k] * Wd[t * 32 + k];
    z[128 + t] = fmaxf(a, 0.f);
  }
  __syncthreads();
  {
    float a = bf1[t];
    for (int k = 0; k < 192; ++k) a += z[k] * Wf1[t * 192 + k];
    z1[t] = fmaxf(a, 0.f);
  }
  __syncthreads();
  if (t < 64) {
    float a = bf2[t];
    for (int k = 0; k < 128; ++k) a += z1[k] * Wf2[t * 128 + k];
    z2[t] = fmaxf(a, 0.f);
  }
  __syncthreads();
  if (t < 64) {
    float v = z2[t] * Wf3[t];
    for (int off = 1; off < 64; off <<= 1) v += __shfl_xor(v, off, 64);
    if (t == 0) out[b] = v + bf3[0];
  }
}

extern "C" void kernel_launch(void* const* d_in, const int* in_sizes, int n_in,
                              void* d_out, int out_size, void* d_ws, size_t ws_size,
                              hipStream_t stream) {
  const float* x      = (const float*)d_in[0];
  const float* domain = (const float*)d_in[1];
  const float* Wl1 = (const float*)d_in[2];  const float* bl1 = (const float*)d_in[3];
  const float* Wr1 = (const float*)d_in[4];  const float* br1 = (const float*)d_in[5];
  const float* att1= (const float*)d_in[6];  const float* bias1=(const float*)d_in[7];
  const float* Wl2 = (const float*)d_in[8];  const float* bl2 = (const float*)d_in[9];
  const float* Wr2 = (const float*)d_in[10]; const float* br2 = (const float*)d_in[11];
  const float* att2= (const float*)d_in[12]; const float* bias2=(const float*)d_in[13];
  const float* Wres= (const float*)d_in[14]; const float* bres= (const float*)d_in[15];
  const float* Wd  = (const float*)d_in[16]; const float* bd  = (const float*)d_in[17];
  const float* Wg  = (const float*)d_in[18]; const float* bg  = (const float*)d_in[19];
  const float* Wf1 = (const float*)d_in[20]; const float* bf1 = (const float*)d_in[21];
  const float* Wf2 = (const float*)d_in[22]; const float* bf2 = (const float*)d_in[23];
  const float* Wf3 = (const float*)d_in[24]; const float* bf3 = (const float*)d_in[25];
  const int* ei    = (const int*)d_in[26];
  const int* batch = (const int*)d_in[27];
  const int* esrc = ei;
  const int* edst = ei + NE;
  float* outp = (float*)d_out;

  char* p = (char*)d_ws;
  auto carve = [&](size_t bytes) { char* r = p; p += (bytes + 255) & ~(size_t)255; return r; };
  int* hist2d   = (int*)carve((size_t)NCHK * NBUK * 4);
  int* coff     = (int*)carve((size_t)NBUK * NCHK * 4);
  int* btot     = (int*)carve((size_t)NBUK * 4);
  int* bbase    = (int*)carve((size_t)(NBUK + 1) * 4);
  int* tmpv     = (int*)carve((size_t)NE * 4);
  int* ssrc     = (int*)carve((size_t)NE * 4);
  int* offs     = (int*)carve((size_t)(NN + 1) * 4);
  unsigned short* wimg = (unsigned short*)carve((size_t)5 * 2 * 8192 * 2);
  unsigned short* ximg = (unsigned short*)carve((size_t)NBLK * 8192 * 2);  // fp16 A image (aliased as himg)
  _Float16* xl  = (_Float16*)carve((size_t)NN * FD * 2);
  _Float16* xr  = (_Float16*)carve((size_t)NN * FD * 2);
  _Float16* res = (_Float16*)carve((size_t)NN * FD * 2);
  float* pooled = (float*)carve((size_t)NB * FD * 4);
  unsigned short* himg = ximg;     // ximg dead after layer-1 linears; alias

  dim3 b256(256);
  // K1: [hist2d(256) | wprep(40) | xprep(3125)]
  hipLaunchKernelGGL(k_prep1, dim3(NCHK + 40 + 3125), b256, 0, stream,
                     Wl1, Wr1, Wres, Wl2, Wr2, wimg, edst, hist2d, x, ximg);
  // K2a: per-bucket chunk scan; K2b: bucket-base scan (+ pooled zero)
  hipLaunchKernelGGL(k_colscan, dim3(NBUK), b256, 0, stream, hist2d, coff, btot);
  hipLaunchKernelGGL(k_bscan2, dim3(1), b256, 0, stream, btot, bbase, pooled);
  // K3: scatter with precomputed offsets (no global atomics)
  hipLaunchKernelGGL(k_bscatter, dim3(NCHK), b256, 0, stream, esrc, edst, bbase, coff, tmpv);
  // K4: [bcsr(196) | linm2 layer-1 (3*NBLK)]
  hipLaunchKernelGGL(k_csrlin, dim3(NBUK + 3 * NBLK), dim3(512), 0, stream,
                     tmpv, bbase, offs, ssrc, ximg, wimg, bl1, br1, bres, xl, xr, res);
  // K5: GAT layer 1 -> himg
  hipLaunchKernelGGL(k_gat1, dim3(NN / 8), b256, 0, stream,
                     xl, xr, offs, ssrc, att1, bias1, res, himg);
  // K6: linm2 layer-2
  hipLaunchKernelGGL(k_lin2, dim3(NBLK, 2), dim3(512), 0, stream,
                     himg, wimg, bl2, br2, xl, xr);
  // K7: GAT layer 2 + pooled accumulation
  hipLaunchKernelGGL(k_gatpool, dim3(NN / 8), b256, 0, stream,
                     xl, xr, offs, ssrc, att2, bias2, himg, batch, pooled);
  // K8: MLP head
  hipLaunchKernelGGL(k_mlp, dim3(NB), dim3(128), 0, stream, pooled, batch, domain,
                     Wg, bg, Wd, bd, Wf1, bf1, Wf2, bf2, Wf3, bf3, outp);
}

// Round 19
// 154.383 us; speedup vs baseline: 1.0534x; 1.0069x over previous
//
#include <hip/hip_runtime.h>
#include <math.h>

#define NN 50000
#define NE 800000
#define FD 128      // IN == HC == 128
#define NB 64
#define NBUK 196            // ceil(NN/256) buckets of 256 dst nodes
#define NCHK 256            // histogram/scatter chunks
#define CHK 3125            // NE / NCHK
#define CAP 6144            // LDS staging capacity per bucket (mean 4082, std ~64)
#define NBLK 782            // ceil(NN/64) 64-row tiles for the linears

typedef __attribute__((ext_vector_type(8))) short short8v;
typedef __attribute__((ext_vector_type(4))) float f32x4;
typedef _Float16 h2 __attribute__((ext_vector_type(2)));
typedef _Float16 h8 __attribute__((ext_vector_type(8)));

// ---------------- fp16 helpers ----------------
__device__ __forceinline__ unsigned short f2h(float f) {
  return __builtin_bit_cast(unsigned short, (_Float16)f);
}
__device__ __forceinline__ float h2f(unsigned short u) {
  return (float)__builtin_bit_cast(_Float16, u);
}

// fp16-single image coords for node n, 32-lane id holding cols 4*lane..4*lane+3
__device__ __forceinline__ size_t img_base(int n, int lane) {
  int lrow = n & 63, blk = n >> 6;
  int kh = lane >> 4, s7 = (lane >> 1) & 7, off4 = (lane & 1) * 4;
  return (size_t)blk * 8192 + kh * 4096 + lrow * 64 + 8 * (s7 ^ (lrow & 7)) + off4;
}

// ================= K1: [hist2d | wprep | xprep] — all independent, no global atomics =====
__global__ __launch_bounds__(256) void k_prep1(const float* __restrict__ W0,
    const float* __restrict__ W1, const float* __restrict__ W2,
    const float* __restrict__ W3, const float* __restrict__ W4,
    unsigned short* __restrict__ wimg,
    const int* __restrict__ dst, int* __restrict__ hist2d,
    const float* __restrict__ x, unsigned short* __restrict__ ximg) {
  __shared__ int bh[NBUK];
  int bx = blockIdx.x;
  if (bx < NCHK) {
    // ---- per-chunk bucket histogram, private row (no global atomics) ----
    int t = threadIdx.x;
    for (int i = t; i < NBUK; i += 256) bh[i] = 0;
    __syncthreads();
    int e0 = bx * CHK, e1 = e0 + CHK;
    if (e1 > NE) e1 = NE;
    for (int e = e0 + t; e < e1; e += 256) atomicAdd(&bh[dst[e] >> 8], 1);
    __syncthreads();
    for (int i = t; i < NBUK; i += 256) hist2d[bx * NBUK + i] = bh[i];
  } else if (bx < NCHK + 40) {
    // ---- wprep: W -> fp16-single pre-swizzled images ----
    int id = (bx - NCHK) * 256 + threadIdx.x;
    if (id >= 5 * 2048) return;
    int w = id >> 11, rem = id & 2047;
    int row = rem >> 4, slot = rem & 15;
    const float* Wp = (w == 0) ? W0 : (w == 1) ? W1 : (w == 2) ? W2 : (w == 3) ? W3 : W4;
    const float* sp = &Wp[row * 128 + slot * 8];
    int kh = slot >> 3, s7 = slot & 7;
    int d = ((w * 2 + kh) * 8192) + row * 64 + 8 * (s7 ^ (row & 7));
    short8v hv;
    #pragma unroll
    for (int j = 0; j < 8; ++j)
      hv[j] = (short)f2h(sp[j]);
    *(short8v*)&wimg[d] = hv;
  } else {
    // ---- xprep: pack x into fp16-single swizzled A-image ----
    int id = (bx - NCHK - 40) * 256 + threadIdx.x;   // < NN*16 = 800000 exactly
    int row = id >> 4, slot = id & 15;
    const float* sp = &x[(size_t)row * 128 + slot * 8];
    int blk = row >> 6, lrow = row & 63, kh = slot >> 3, s7 = slot & 7;
    size_t hoff = (size_t)blk * 8192 + kh * 4096 + lrow * 64 + 8 * (s7 ^ (lrow & 7));
    short8v hv;
    #pragma unroll
    for (int j = 0; j < 8; ++j)
      hv[j] = (short)f2h(sp[j]);
    *(short8v*)&ximg[hoff] = hv;
  }
}

// ================= K2: per-bucket scan over 256 chunk counts (+ bbase + pooled zero) ====
// Block b: coff[b*256+c] = sum_{c'<c} hist2d[c'][b]; btot[b] = bucket total.
// Block 0 also zeroes pooled.
__global__ __launch_bounds__(256) void k_colscan(const int* __restrict__ hist2d,
    int* __restrict__ coff, int* __restrict__ btot, float* __restrict__ pooled) {
  __shared__ int ws[4];
  int b = blockIdx.x, t = threadIdx.x;
  if (b == 0) {
    float4 z4 = make_float4(0.f, 0.f, 0.f, 0.f);
    #pragma unroll
    for (int i = 0; i < 8; ++i)
      ((float4*)pooled)[i * 256 + t] = z4;   // 8*256*4 = 8192 floats
  }
  int v = hist2d[t * NBUK + b];
  int lane = t & 63, wv = t >> 6;
  int s = v;
  #pragma unroll
  for (int off = 1; off < 64; off <<= 1) {
    int y = __shfl_up(s, off, 64);
    if (lane >= off) s += y;
  }
  if (lane == 63) ws[wv] = s;
  __syncthreads();
  if (t == 0) {
    int r = 0;
    #pragma unroll
    for (int i = 0; i < 4; ++i) { int x = ws[i]; ws[i] = r; r += x; }
  }
  __syncthreads();
  int excl = s - v + ws[wv];
  coff[b * 256 + t] = excl;
  if (t == 255) btot[b] = excl + v;
}

// ================= K3: scatter; bucket bases computed inline from btot =========
// Each block scans btot[196] locally (exclusive prefix) -> bbase; block 0 persists it.
// pkt = (src << 8) | (dst & 255)
__global__ __launch_bounds__(256) void k_bscatter(const int* __restrict__ src,
    const int* __restrict__ dst, const int* __restrict__ btot,
    const int* __restrict__ coff, int* __restrict__ tmpv,
    int* __restrict__ bbase) {
  __shared__ int bb[NBUK];
  __shared__ int brun[NBUK];
  __shared__ int wsum[4];
  int c = blockIdx.x, t = threadIdx.x;
  // local exclusive scan of btot -> bucket base
  int v = (t < NBUK) ? btot[t] : 0;
  int lane = t & 63, wv = t >> 6;
  int s = v;
  #pragma unroll
  for (int off = 1; off < 64; off <<= 1) {
    int y = __shfl_up(s, off, 64);
    if (lane >= off) s += y;
  }
  if (lane == 63) wsum[wv] = s;
  __syncthreads();
  if (t == 0) {
    int r = 0;
    #pragma unroll
    for (int i = 0; i < 4; ++i) { int x = wsum[i]; wsum[i] = r; r += x; }
  }
  __syncthreads();
  int excl = s - v + wsum[wv];
  if (t < NBUK) {
    bb[t] = excl + coff[t * 256 + c];
    brun[t] = 0;
    if (c == 0) bbase[t] = excl;
  }
  if (c == 0 && t == NBUK - 1) bbase[NBUK] = excl + v;
  __syncthreads();
  int e0 = c * CHK, e1 = e0 + CHK;
  if (e1 > NE) e1 = NE;
  for (int e = e0 + t; e < e1; e += 256) {
    int d = dst[e];
    int bk = d >> 8;
    int p = bb[bk] + atomicAdd(&brun[bk], 1);
    tmpv[p] = (src[e] << 8) | (d & 255);
  }
}

// ---------------- MFMA linear body: fp16 A x fp16 W (single), 1 MFMA/slice ----------
__device__ __forceinline__ void linm2_body(
    const unsigned short* __restrict__ aimg,
    const unsigned short* __restrict__ w_img,
    int wimg, const float* __restrict__ bias,
    _Float16* __restrict__ out_h, int blk, char* smem) {
  unsigned short* s_a = (unsigned short*)smem;           // 8 KB
  unsigned short* s_w = s_a + 4096;                      // 16 KB
  const int tid = threadIdx.x;
  const int lane = tid & 63;
  const int wv = tid >> 6;
  const int m0 = (wv >> 2) * 32;
  const int n0 = (wv & 3) * 32;
  const int rbase = blk * 64;
  const int g = lane >> 4, lr = lane & 15;

  f32x4 acc[2][2];
  #pragma unroll
  for (int mt = 0; mt < 2; ++mt)
    #pragma unroll
    for (int nt = 0; nt < 2; ++nt)
      acc[mt][nt] = (f32x4){0.f, 0.f, 0.f, 0.f};

  for (int kh = 0; kh < 2; ++kh) {
    if (kh) __syncthreads();
    {
      const short8v* asrc = (const short8v*)(aimg + (size_t)blk * 8192 + kh * 4096);
      ((short8v*)s_a)[tid] = asrc[tid];                  // 512 x 16B = 8 KB
    }
    {
      const short8v* wsrc = (const short8v*)(w_img + (size_t)(wimg * 2 + kh) * 8192);
      short8v* wd = (short8v*)s_w;
      wd[tid] = wsrc[tid];
      wd[512 + tid] = wsrc[512 + tid];                   // 16 KB
    }
    __syncthreads();
    #pragma unroll
    for (int ks = 0; ks < 2; ++ks) {
      const int slot = ks * 4 + g;
      h8 a[2];
      #pragma unroll
      for (int mt = 0; mt < 2; ++mt) {
        int row = m0 + mt * 16 + lr;
        int idx = row * 64 + 8 * (slot ^ (row & 7));
        a[mt] = __builtin_bit_cast(h8, *(const short8v*)&s_a[idx]);
      }
      #pragma unroll
      for (int nt = 0; nt < 2; ++nt) {
        int row2 = n0 + nt * 16 + lr;
        int idx2 = row2 * 64 + 8 * (slot ^ (row2 & 7));
        h8 b = __builtin_bit_cast(h8, *(const short8v*)&s_w[idx2]);
        #pragma unroll
        for (int mt = 0; mt < 2; ++mt)
          acc[mt][nt] = __builtin_amdgcn_mfma_f32_16x16x32_f16(a[mt], b, acc[mt][nt], 0, 0, 0);
      }
    }
  }
  #pragma unroll
  for (int nt = 0; nt < 2; ++nt) {
    float bv = bias[n0 + nt * 16 + lr];
    #pragma unroll
    for (int mt = 0; mt < 2; ++mt)
      #pragma unroll
      for (int i = 0; i < 4; ++i) {
        int r = rbase + m0 + mt * 16 + 4 * g + i;
        if (r < NN) {
          float vv = acc[mt][nt][i] + bv;
          out_h[(size_t)r * 128 + n0 + nt * 16 + lr] = (_Float16)vv;
        }
      }
  }
}

// ================= K4: [bcsr | linm2 layer-1 (3 matrices)] =================
__global__ __launch_bounds__(512, 8) void k_csrlin(
    const int* __restrict__ tmpv, const int* __restrict__ bbase,
    int* __restrict__ offs, int* __restrict__ ssrc,
    const unsigned short* __restrict__ ximg,
    const unsigned short* __restrict__ w_img,
    const float* __restrict__ bl1, const float* __restrict__ br1, const float* __restrict__ bres,
    _Float16* __restrict__ xl, _Float16* __restrict__ xr,
    _Float16* __restrict__ res) {
  __shared__ __align__(16) char smem[28672];   // bcsr needs 26.7 KB; GEMM uses 24 KB
  int bx = blockIdx.x;
  if (bx < NBUK) {
    int* sdeg = (int*)smem;
    int* scur = sdeg + 256;
    int* wsum = scur + 256;
    int* lsrc = wsum + 16;
    int b = bx, t = threadIdx.x;
    int es = bbase[b], ee = bbase[b + 1];
    int cnt = ee - es;
    if (t < 256) sdeg[t] = 0;
    __syncthreads();
    for (int i = t; i < cnt; i += 512) atomicAdd(&sdeg[tmpv[es + i] & 255], 1);
    __syncthreads();
    int v = 0, s = 0;
    int lane = t & 63, wv = t >> 6;
    if (t < 256) {
      v = sdeg[t];
      s = v;
      #pragma unroll
      for (int off = 1; off < 64; off <<= 1) {
        int y = __shfl_up(s, off, 64);
        if (lane >= off) s += y;
      }
      if (lane == 63) wsum[wv] = s;
    }
    __syncthreads();
    if (t == 0) {
      int r = 0;
      #pragma unroll
      for (int i = 0; i < 4; ++i) { int x2 = wsum[i]; wsum[i] = r; r += x2; }
    }
    __syncthreads();
    if (t < 256) {
      int excl = s - v + wsum[wv];
      scur[t] = excl;
      int node = b * 256 + t;
      if (node < NN) offs[node] = es + excl;
    }
    if (b == 0 && t == 0) offs[NN] = NE;
    __syncthreads();
    if (cnt <= CAP) {
      for (int i = t; i < cnt; i += 512) {
        int pkt = tmpv[es + i];
        int p = atomicAdd(&scur[pkt & 255], 1);
        lsrc[p] = pkt >> 8;
      }
      __syncthreads();
      for (int i = t; i < cnt; i += 512) ssrc[es + i] = lsrc[i];
    } else {
      for (int i = t; i < cnt; i += 512) {
        int pkt = tmpv[es + i];
        int p = atomicAdd(&scur[pkt & 255], 1);
        ssrc[es + p] = pkt >> 8;
      }
    }
  } else {
    int bf = bx - NBUK;
    int w = bf / NBLK, blk = bf % NBLK;
    const float* bias = (w == 0) ? bl1 : (w == 1) ? br1 : bres;
    _Float16* oh = (w == 0) ? xl : (w == 1) ? xr : res;
    linm2_body(ximg, w_img, w, bias, oh, blk, smem);
  }
}

// ================= K6: linm2 layer-2 (2 matrices) =================
__global__ __launch_bounds__(512, 8) void k_lin2(
    const unsigned short* __restrict__ himg,
    const unsigned short* __restrict__ w_img,
    const float* __restrict__ bl2, const float* __restrict__ br2,
    _Float16* __restrict__ xl, _Float16* __restrict__ xr) {
  __shared__ __align__(16) char smem[28672];
  int w = blockIdx.y;
  linm2_body(himg, w_img, 3 + w, (w == 0) ? bl2 : br2,
             (w == 0) ? xl : xr, blockIdx.x, smem);
}

// ---------------- GATv2 core: fp16 packed edge math, no-max softmax, 4-wide MLP ------
__device__ __forceinline__ float4 gat_core(const _Float16* __restrict__ xl,
    const _Float16* __restrict__ xr, const int* __restrict__ offs,
    const int* __restrict__ ssrc, const float* __restrict__ att,
    const float* __restrict__ bias, int n, int lane) {
  float4 att4 = ((const float4*)att)[lane];
  h2 att01 = {(_Float16)att4.x, (_Float16)att4.y};
  h2 att23 = {(_Float16)att4.z, (_Float16)att4.w};
  uint2 xru = ((const uint2*)xr)[(size_t)n * 32 + lane];
  h2 xr01 = __builtin_bit_cast(h2, xru.x);
  h2 xr23 = __builtin_bit_cast(h2, xru.y);
  const h2 k02 = {(_Float16)0.2f, (_Float16)0.2f};
  int e0 = offs[n], e1 = offs[n + 1];
  float den = 0.f;
  float4 acc = make_float4(0.f, 0.f, 0.f, 0.f);
  int e = e0;
  for (; e + 3 < e1; e += 4) {
    uint2 u[4];
    #pragma unroll
    for (int j = 0; j < 4; ++j) {
      int s = ssrc[e + j];
      u[j] = ((const uint2*)xl)[(size_t)s * 32 + lane];
    }
    #pragma unroll
    for (int j = 0; j < 4; ++j) {
      h2 v01 = __builtin_bit_cast(h2, u[j].x);
      h2 v23 = __builtin_bit_cast(h2, u[j].y);
      h2 t01 = v01 + xr01;
      h2 t23 = v23 + xr23;
      h2 l01 = __builtin_elementwise_max(t01, t01 * k02);
      h2 l23 = __builtin_elementwise_max(t23, t23 * k02);
      float p = __builtin_amdgcn_fdot2(l01, att01, 0.f, false);
      p = __builtin_amdgcn_fdot2(l23, att23, p, false);
      p += __shfl_xor(p, 1, 64); p += __shfl_xor(p, 2, 64); p += __shfl_xor(p, 4, 64);
      float w = __expf(p);
      den += w;
      acc.x += w * (float)v01[0];
      acc.y += w * (float)v01[1];
      acc.z += w * (float)v23[0];
      acc.w += w * (float)v23[1];
    }
  }
  for (; e < e1; ++e) {
    int s = ssrc[e];
    uint2 uu = ((const uint2*)xl)[(size_t)s * 32 + lane];
    h2 v01 = __builtin_bit_cast(h2, uu.x);
    h2 v23 = __builtin_bit_cast(h2, uu.y);
    h2 t01 = v01 + xr01;
    h2 t23 = v23 + xr23;
    h2 l01 = __builtin_elementwise_max(t01, t01 * k02);
    h2 l23 = __builtin_elementwise_max(t23, t23 * k02);
    float p = __builtin_amdgcn_fdot2(l01, att01, 0.f, false);
    p = __builtin_amdgcn_fdot2(l23, att23, p, false);
    p += __shfl_xor(p, 1, 64); p += __shfl_xor(p, 2, 64); p += __shfl_xor(p, 4, 64);
    float w = __expf(p);
    den += w;
    acc.x += w * (float)v01[0];
    acc.y += w * (float)v01[1];
    acc.z += w * (float)v23[0];
    acc.w += w * (float)v23[1];
  }
  float inv = (den > 0.f) ? 1.f / den : 0.f;
  float4 b4 = ((const float4*)bias)[lane];
  float4 o;
  o.x = fmaxf(acc.x * inv + b4.x, 0.f);
  o.y = fmaxf(acc.y * inv + b4.y, 0.f);
  o.z = fmaxf(acc.z * inv + b4.z, 0.f);
  o.w = fmaxf(acc.w * inv + b4.w, 0.f);
  return o;
}

// ================= K5: GAT layer 1 — writes ONLY the fp16 himg image =================
__global__ __launch_bounds__(256) void k_gat1(const _Float16* __restrict__ xl,
    const _Float16* __restrict__ xr, const int* __restrict__ offs,
    const int* __restrict__ ssrc, const float* __restrict__ att,
    const float* __restrict__ bias, const _Float16* __restrict__ resid,
    unsigned short* __restrict__ himg) {
  int grp = threadIdx.x >> 5;
  int lane = threadIdx.x & 31;
  int n = blockIdx.x * 8 + grp;     // NN % 8 == 0: always valid
  float4 o = gat_core(xl, xr, offs, ssrc, att, bias, n, lane);
  uint2 ru = ((const uint2*)resid)[(size_t)n * 32 + lane];
  h2 r01 = __builtin_bit_cast(h2, ru.x);
  h2 r23 = __builtin_bit_cast(h2, ru.y);
  o.x += (float)r01[0]; o.y += (float)r01[1];
  o.z += (float)r23[0]; o.w += (float)r23[1];
  size_t base = img_base(n, lane);
  ushort4 hv;
  hv.x = f2h(o.x); hv.y = f2h(o.y); hv.z = f2h(o.z); hv.w = f2h(o.w);
  *(ushort4*)&himg[base] = hv;
}

// ================= K7: GAT layer 2 + fused mean-pool accumulation =================
__global__ __launch_bounds__(256) void k_gatpool(const _Float16* __restrict__ xl,
    const _Float16* __restrict__ xr, const int* __restrict__ offs,
    const int* __restrict__ ssrc, const float* __restrict__ att,
    const float* __restrict__ bias, const unsigned short* __restrict__ himg,
    const int* __restrict__ batch, float* __restrict__ pooled) {
  __shared__ float sm[8][128];
  __shared__ int sbat[8];
  int grp = threadIdx.x >> 5;
  int lane = threadIdx.x & 31;
  int n = blockIdx.x * 8 + grp;
  float4 o = gat_core(xl, xr, offs, ssrc, att, bias, n, lane);
  size_t base = img_base(n, lane);
  ushort4 rh = *(const ushort4*)&himg[base];
  o.x += h2f(rh.x); o.y += h2f(rh.y); o.z += h2f(rh.z); o.w += h2f(rh.w);
  *(float4*)&sm[grp][lane * 4] = o;
  if (threadIdx.x < 8) sbat[threadIdx.x] = batch[blockIdx.x * 8 + threadIdx.x];
  __syncthreads();
  int t = threadIdx.x;
  if (t < 128) {
    float run = sm[0][t];
    int cb = sbat[0];
    #pragma unroll
    for (int g2 = 1; g2 < 8; ++g2) {
      int bb = sbat[g2];
      if (bb != cb) { atomicAdd(&pooled[cb * FD + t], run); run = 0.f; cb = bb; }
      run += sm[g2][t];
    }
    atomicAdd(&pooled[cb * FD + t], run);
  }
}

// ================= K8: MLP head =================
__global__ __launch_bounds__(128) void k_mlp(const float* __restrict__ pooled,
    const int* __restrict__ batch, const float* __restrict__ domain,
    const float* __restrict__ Wg, const float* __restrict__ bg,
    const float* __restrict__ Wd, const float* __restrict__ bd,
    const float* __restrict__ Wf1, const float* __restrict__ bf1,
    const float* __restrict__ Wf2, const float* __restrict__ bf2,
    const float* __restrict__ Wf3, const float* __restrict__ bf3,
    float* __restrict__ out) {
  __shared__ float z[192];
  __shared__ float z1[128];
  __shared__ float z2[64];
  __shared__ float pm[128];
  __shared__ int cnt;
  int b = blockIdx.x, t = threadIdx.x;
  if (t == 0) {
    int lo = 0, hi = NN;
    while (lo < hi) { int mid = (lo + hi) >> 1; if (batch[mid] < b) lo = mid + 1; else hi = mid; }
    int lb = lo; lo = 0; hi = NN;
    while (lo < hi) { int mid = (lo + hi) >> 1; if (batch[mid] < b + 1) lo = mid + 1; else hi = mid; }
    cnt = lo - lb;
  }
  __syncthreads();
  float invc = 1.f / fmaxf((float)cnt, 1.f);
  pm[t] = pooled[b * FD + t] * invc;
  __syncthreads();
  {
    float a = bg[t];
    for (int k = 0; k < 128; ++k) a += pm[k] * Wg[t * 128 + k];
    z[t] = fmaxf(a, 0.f);
  }
  if (t < 64) {
    float a = bd[t];
    for (int k = 0; k < 32; ++k) a += domain[b * 32 + k] * Wd[t * 32 + k];
    z[128 + t] = fmaxf(a, 0.f);
  }
  __syncthreads();
  {
    float a = bf1[t];
    for (int k = 0; k < 192; ++k) a += z[k] * Wf1[t * 192 + k];
    z1[t] = fmaxf(a, 0.f);
  }
  __syncthreads();
  if (t < 64) {
    float a = bf2[t];
    for (int k = 0; k < 128; ++k) a += z1[k] * Wf2[t * 128 + k];
    z2[t] = fmaxf(a, 0.f);
  }
  __syncthreads();
  if (t < 64) {
    float v = z2[t] * Wf3[t];
    for (int off = 1; off < 64; off <<= 1) v += __shfl_xor(v, off, 64);
    if (t == 0) out[b] = v + bf3[0];
  }
}

extern "C" void kernel_launch(void* const* d_in, const int* in_sizes, int n_in,
                              void* d_out, int out_size, void* d_ws, size_t ws_size,
                              hipStream_t stream) {
  const float* x      = (const float*)d_in[0];
  const float* domain = (const float*)d_in[1];
  const float* Wl1 = (const float*)d_in[2];  const float* bl1 = (const float*)d_in[3];
  const float* Wr1 = (const float*)d_in[4];  const float* br1 = (const float*)d_in[5];
  const float* att1= (const float*)d_in[6];  const float* bias1=(const float*)d_in[7];
  const float* Wl2 = (const float*)d_in[8];  const float* bl2 = (const float*)d_in[9];
  const float* Wr2 = (const float*)d_in[10]; const float* br2 = (const float*)d_in[11];
  const float* att2= (const float*)d_in[12]; const float* bias2=(const float*)d_in[13];
  const float* Wres= (const float*)d_in[14]; const float* bres= (const float*)d_in[15];
  const float* Wd  = (const float*)d_in[16]; const float* bd  = (const float*)d_in[17];
  const float* Wg  = (const float*)d_in[18]; const float* bg  = (const float*)d_in[19];
  const float* Wf1 = (const float*)d_in[20]; const float* bf1 = (const float*)d_in[21];
  const float* Wf2 = (const float*)d_in[22]; const float* bf2 = (const float*)d_in[23];
  const float* Wf3 = (const float*)d_in[24]; const float* bf3 = (const float*)d_in[25];
  const int* ei    = (const int*)d_in[26];
  const int* batch = (const int*)d_in[27];
  const int* esrc = ei;
  const int* edst = ei + NE;
  float* outp = (float*)d_out;

  char* p = (char*)d_ws;
  auto carve = [&](size_t bytes) { char* r = p; p += (bytes + 255) & ~(size_t)255; return r; };
  int* hist2d   = (int*)carve((size_t)NCHK * NBUK * 4);
  int* coff     = (int*)carve((size_t)NBUK * NCHK * 4);
  int* btot     = (int*)carve((size_t)NBUK * 4);
  int* bbase    = (int*)carve((size_t)(NBUK + 1) * 4);
  int* tmpv     = (int*)carve((size_t)NE * 4);
  int* ssrc     = (int*)carve((size_t)NE * 4);
  int* offs     = (int*)carve((size_t)(NN + 1) * 4);
  unsigned short* wimg = (unsigned short*)carve((size_t)5 * 2 * 8192 * 2);
  unsigned short* ximg = (unsigned short*)carve((size_t)NBLK * 8192 * 2);  // fp16 A image (aliased as himg)
  _Float16* xl  = (_Float16*)carve((size_t)NN * FD * 2);
  _Float16* xr  = (_Float16*)carve((size_t)NN * FD * 2);
  _Float16* res = (_Float16*)carve((size_t)NN * FD * 2);
  float* pooled = (float*)carve((size_t)NB * FD * 4);
  unsigned short* himg = ximg;     // ximg dead after layer-1 linears; alias

  dim3 b256(256);
  // K1: [hist2d(256) | wprep(40) | xprep(3125)]
  hipLaunchKernelGGL(k_prep1, dim3(NCHK + 40 + 3125), b256, 0, stream,
                     Wl1, Wr1, Wres, Wl2, Wr2, wimg, edst, hist2d, x, ximg);
  // K2: per-bucket chunk scan (+ pooled zero in block 0)
  hipLaunchKernelGGL(k_colscan, dim3(NBUK), b256, 0, stream, hist2d, coff, btot, pooled);
  // K3: scatter with inline bucket-base scan (writes bbase as a side effect)
  hipLaunchKernelGGL(k_bscatter, dim3(NCHK), b256, 0, stream, esrc, edst, btot, coff, tmpv, bbase);
  // K4: [bcsr(196) | linm2 layer-1 (3*NBLK)]
  hipLaunchKernelGGL(k_csrlin, dim3(NBUK + 3 * NBLK), dim3(512), 0, stream,
                     tmpv, bbase, offs, ssrc, ximg, wimg, bl1, br1, bres, xl, xr, res);
  // K5: GAT layer 1 -> himg
  hipLaunchKernelGGL(k_gat1, dim3(NN / 8), b256, 0, stream,
                     xl, xr, offs, ssrc, att1, bias1, res, himg);
  // K6: linm2 layer-2
  hipLaunchKernelGGL(k_lin2, dim3(NBLK, 2), dim3(512), 0, stream,
                     himg, wimg, bl2, br2, xl, xr);
  // K7: GAT layer 2 + pooled accumulation
  hipLaunchKernelGGL(k_gatpool, dim3(NN / 8), b256, 0, stream,
                     xl, xr, offs, ssrc, att2, bias2, himg, batch, pooled);
  // K8: MLP head
  hipLaunchKernelGGL(k_mlp, dim3(NB), dim3(128), 0, stream, pooled, batch, domain,
                     Wg, bg, Wd, bd, Wf1, bf1, Wf2, bf2, Wf3, bf3, outp);
}